// Round 12
// baseline (193.231 us; speedup 1.0000x reference)
//
#include <hip/hip_runtime.h>

#define HW 65536
#define CB 64
#define NB 8

typedef __attribute__((ext_vector_type(4))) float f32x4;
typedef __attribute__((ext_vector_type(8))) short s16x8;

__device__ __forceinline__ float sigm(float v) { return 1.f / (1.f + __expf(-v)); }

__device__ __forceinline__ unsigned f2bf(float f) {  // RNE, low 16 bits
    unsigned u = __float_as_uint(f);
    u += 0x7fffu + ((u >> 16) & 1u);
    return u >> 16;
}
__device__ __forceinline__ float bf2f(unsigned h) {
    return __uint_as_float(h << 16);
}
// swizzled word index for [row][32-word] bf16 tiles (row stride 128B)
__device__ __forceinline__ int swz(int row, int w) { return (row << 5) + (w ^ ((row & 7) << 2)); }

// ---------------------------------------------------------------------------
// P1 (k_pre): one pass over fp32 x ->
//   sm (per-px packed bf16 {channel-mean, channel-max}),
//   xpc (bf16 [px][64ch] copy via swizzled LDS transpose, coalesced dump),
//   per-channel pool sum/max partials (per-block slots, NO atomics/zeroing).
// Tail blocks (>=2048): convert gate/dsc weights to swizzled bf16 wbuf and
// zero the 1280-float gn/bn stats scratch.
__global__ __launch_bounds__(256) void k_pre(
    const float* __restrict__ x, unsigned short* __restrict__ xpc,
    float* __restrict__ pool_scr, float* __restrict__ pmax_scr,
    unsigned* __restrict__ sm,
    const float* __restrict__ gw, const float* __restrict__ dw,
    unsigned* __restrict__ wbuf, float* __restrict__ zstats)
{
    const int t = threadIdx.x;
    if (blockIdx.x >= NB * 256) {          // ---- tail: init work ----
        const int ex = blockIdx.x - NB * 256;
        if (ex < 2) {
            const float* src = (ex == 0) ? gw : dw;
            unsigned* dst = wbuf + (ex << 11);
            const int orow = t >> 2, cq = (t & 3) << 4;
            const float* s = src + (orow << 6) + cq;
            unsigned u[8];
            #pragma unroll
            for (int j = 0; j < 8; ++j)
                u[j] = f2bf(s[2 * j]) | (f2bf(s[2 * j + 1]) << 16);
            const int wbase = (t & 3) << 3;
            *(uint4*)&dst[swz(orow, wbase)]     = make_uint4(u[0], u[1], u[2], u[3]);
            *(uint4*)&dst[swz(orow, wbase + 4)] = make_uint4(u[4], u[5], u[6], u[7]);
        } else {
            #pragma unroll
            for (int k2 = 0; k2 < 5; ++k2) zstats[k2 * 256 + t] = 0.f;
        }
        return;
    }

    __shared__ unsigned tile[8192];   // [256px][32 words] bf16, swizzled
    __shared__ float scrS[8][64];
    __shared__ float scrM[8][64];
    const int b = blockIdx.x >> 8;
    const int pbase = (blockIdx.x & 255) << 8;
    const size_t xb = ((size_t)(b << 6)) * HW + pbase + t;
    const int s = (t & 7) << 2;       // swizzle term for this thread's row

    float psum = 0.f, pmax = -1e30f;
    #pragma unroll
    for (int cg = 0; cg < 4; ++cg) {  // 16 channels per batch, all loads independent
        float v[16];
        #pragma unroll
        for (int k = 0; k < 16; ++k)
            v[k] = x[xb + (size_t)((cg << 4) + k) * HW];
        #pragma unroll
        for (int k = 0; k < 16; ++k) { psum += v[k]; pmax = fmaxf(pmax, v[k]); }
        unsigned w[8];
        #pragma unroll
        for (int k = 0; k < 8; ++k) w[k] = f2bf(v[2 * k]) | (f2bf(v[2 * k + 1]) << 16);
        *(uint4*)&tile[(t << 5) + (((cg << 3)) ^ s)]     = make_uint4(w[0], w[1], w[2], w[3]);
        *(uint4*)&tile[(t << 5) + (((cg << 3) + 4) ^ s)] = make_uint4(w[4], w[5], w[6], w[7]);
    }
    sm[(size_t)b * HW + pbase + t] = f2bf(psum * (1.f / 64.f)) | (f2bf(pmax) << 16);
    __syncthreads();

    // transposed per-channel reduce: cp = word (2 channels), q = px octant
    {
        const int cp = t & 31, q = t >> 5;
        float s0 = 0.f, s1 = 0.f, m0 = -1e30f, m1 = -1e30f;
        #pragma unroll 8
        for (int i = 0; i < 32; ++i) {
            const int px = (q << 5) + i;
            const unsigned u = tile[(px << 5) + (cp ^ ((px & 7) << 2))];
            const float a0 = bf2f(u & 0xffffu), a1 = bf2f(u >> 16);
            s0 += a0; s1 += a1;
            m0 = fmaxf(m0, a0); m1 = fmaxf(m1, a1);
        }
        scrS[q][2 * cp] = s0; scrS[q][2 * cp + 1] = s1;
        scrM[q][2 * cp] = m0; scrM[q][2 * cp + 1] = m1;
    }
    // coalesced xpc dump: thread t writes 16B at flat offset k*4096 + t*16
    {
        unsigned short* xp = xpc + (((size_t)b * HW + pbase) << 6);
        #pragma unroll
        for (int k = 0; k < 8; ++k) {
            const int px = (k << 5) + (t >> 3);
            const int w = ((t & 7) << 2) ^ ((px & 7) << 2);
            const uint4 v = *(const uint4*)&tile[(px << 5) + w];
            *(uint4*)(xp + (k << 11) + (t << 3)) = v;
        }
    }
    __syncthreads();
    if (t < 64) {        // per-block pool slot (no atomics, no init needed)
        float ss = 0.f, mm = -1e30f;
        #pragma unroll
        for (int q = 0; q < 8; ++q) { ss += scrS[q][t]; mm = fmaxf(mm, scrM[q][t]); }
        pool_scr[((size_t)blockIdx.x << 6) + t] = ss;
        pmax_scr[((size_t)blockIdx.x << 6) + t] = mm;
    }
}

// ---------------------------------------------------------------------------
// P2: 7x7 spatial-attention conv over packed bf16 {mean,max} maps + (row-0
// blocks) channel-attention MLP. sa -> bf16.
__global__ __launch_bounds__(256) void k_sa_ca(
    const unsigned* __restrict__ sm, const float* __restrict__ w,
    const float* __restrict__ pool_scr, const float* __restrict__ pmax_scr,
    const float* __restrict__ w1, const float* __restrict__ w2,
    unsigned short* __restrict__ sa, float* __restrict__ ca)
{
    const int t = threadIdx.x;
    const int b = blockIdx.x >> 8;
    const int pix = ((blockIdx.x & 255) << 8) | t;
    const int i = pix >> 8, j = pix & 255;
    const unsigned* src = sm + (size_t)b * HW;
    float acc = 0.f;
    #pragma unroll
    for (int ki = 0; ki < 7; ++ki) {
        const int y = i + ki - 3;
        if ((unsigned)y < 256u) {
            #pragma unroll
            for (int kj = 0; kj < 7; ++kj) {
                const int xx = j + kj - 3;
                if ((unsigned)xx < 256u) {
                    const unsigned u = src[(y << 8) | xx];
                    acc += bf2f(u & 0xffffu) * w[ki * 7 + kj] +
                           bf2f(u >> 16)     * w[49 + ki * 7 + kj];
                }
            }
        }
    }
    sa[(size_t)b * HW + pix] = (unsigned short)f2bf(sigm(acc));

    if ((blockIdx.x & 255) == 0) {   // block-uniform branch: also compute ca[b]
        __shared__ float av[CB], mv[CB], hh[8];
        if (t < CB) {
            float ss = 0.f, mm = -1e30f;
            for (int r = 0; r < 256; ++r) {
                ss += pool_scr[(((size_t)(b << 8) + r) << 6) + t];
                mm = fmaxf(mm, pmax_scr[(((size_t)(b << 8) + r) << 6) + t]);
            }
            av[t] = ss * (1.f / (float)HW);
            mv[t] = mm;
        }
        __syncthreads();
        if (t < 8) {
            const int h = t & 3;
            const float* v = (t < 4) ? av : mv;
            float ssum = 0;
            for (int c = 0; c < CB; ++c) ssum += w1[h * CB + c] * v[c];
            hh[t] = fmaxf(ssum, 0.f);
        }
        __syncthreads();
        if (t < CB) {
            float ssum = 0;
            #pragma unroll
            for (int h = 0; h < 4; ++h) ssum += w2[t * 4 + h] * (hh[h] + hh[4 + h]);
            ca[b * CB + t] = sigm(ssum);
        }
    }
}

// ---------------------------------------------------------------------------
// P3 (k_main): MFMA main. 128-px tile/block, 4 waves, 4 blocks/CU (33KB LDS).
// A-fragments direct from pre-swizzled wbuf (L2). XT staging fused with FT
// compute. Two MFMA GEMMs; d + GN partials out.
__global__ __launch_bounds__(256, 4) void k_main(
    const unsigned short* __restrict__ xpc, const unsigned short* __restrict__ sa,
    const float* __restrict__ ca, const unsigned* __restrict__ wbuf,
    const float* __restrict__ db,
    unsigned short* __restrict__ dbuf, float* __restrict__ gn_sum,
    float* __restrict__ gn_sq)
{
    __shared__ unsigned lds[8224];
    const int t = threadIdx.x;
    const int wv = t >> 6, l = t & 63, hi = l >> 4, lo = l & 15;
    const int b = blockIdx.x >> 9;
    const int pbase = (blockIdx.x & 511) << 7;

    // ---- A-fragments from pre-swizzled global wbuf (registers) ----
    const int arow = (wv << 4) + lo;
    const s16x8 ag0 = __builtin_bit_cast(s16x8, *(const uint4*)&wbuf[swz(arow, hi << 2)]);
    const s16x8 ag1 = __builtin_bit_cast(s16x8, *(const uint4*)&wbuf[swz(arow, (hi << 2) + 16)]);
    const s16x8 ad0 = __builtin_bit_cast(s16x8, *(const uint4*)&wbuf[2048 + swz(arow, hi << 2)]);
    const s16x8 ad1 = __builtin_bit_cast(s16x8, *(const uint4*)&wbuf[2048 + swz(arow, (hi << 2) + 16)]);

    // ---- stage XT (@4096) + FT (@0) fused: FT = x * (sa + ca) ----
    {
        const unsigned short* xp = xpc + (((size_t)b * HW + pbase) << 6);
        #pragma unroll
        for (int k = 0; k < 4; ++k) {
            const int idx = (k << 8) + t;      // 16B chunk id, flat
            const int px = idx >> 3;
            const int ch0 = (idx & 7) << 3;    // first channel of chunk
            const int wg = (idx & 7) << 2;     // logical word group
            const uint4 v = *(const uint4*)(xp + (idx << 3));
            const float sv = bf2f(sa[(size_t)b * HW + pbase + px]);
            const float4 cv0 = *(const float4*)(ca + (b << 6) + ch0);
            const float4 cv1 = *(const float4*)(ca + (b << 6) + ch0 + 4);
            uint4 fv;
            fv.x = f2bf(bf2f(v.x & 0xffffu) * (sv + cv0.x)) |
                   (f2bf(bf2f(v.x >> 16)    * (sv + cv0.y)) << 16);
            fv.y = f2bf(bf2f(v.y & 0xffffu) * (sv + cv0.z)) |
                   (f2bf(bf2f(v.y >> 16)    * (sv + cv0.w)) << 16);
            fv.z = f2bf(bf2f(v.z & 0xffffu) * (sv + cv1.x)) |
                   (f2bf(bf2f(v.z >> 16)    * (sv + cv1.y)) << 16);
            fv.w = f2bf(bf2f(v.w & 0xffffu) * (sv + cv1.z)) |
                   (f2bf(bf2f(v.w >> 16)    * (sv + cv1.w)) << 16);
            const int off = (px << 5) + (wg ^ ((px & 7) << 2));
            *(uint4*)&lds[4096 + off] = v;     // XT
            *(uint4*)&lds[off]        = fv;    // FT
        }
    }
    __syncthreads();

    // ---- GEMM1: guide logits = gate_w @ fuse ----
    f32x4 acc[8];
    #pragma unroll
    for (int n = 0; n < 8; ++n) acc[n] = (f32x4){0.f, 0.f, 0.f, 0.f};
    #pragma unroll
    for (int n = 0; n < 8; ++n) {
        const int brow = (n << 4) + lo;
        const s16x8 b0 = __builtin_bit_cast(s16x8, *(const uint4*)&lds[swz(brow, hi << 2)]);
        const s16x8 b1 = __builtin_bit_cast(s16x8, *(const uint4*)&lds[swz(brow, (hi << 2) + 16)]);
        acc[n] = __builtin_amdgcn_mfma_f32_16x16x32_bf16(ag0, b0, acc[n], 0, 0, 0);
        acc[n] = __builtin_amdgcn_mfma_f32_16x16x32_bf16(ag1, b1, acc[n], 0, 0, 0);
    }
    __syncthreads();

    // ---- xg = x * sigmoid(logit) * mask, XT(@4096) -> FT(@0) ----
    {
        const bool row255 = (pbase >> 8) == 255;
        const bool halfblk = (pbase & 128) != 0;
        const int wb2 = (wv << 3) + (hi << 1);
        #pragma unroll
        for (int n = 0; n < 8; ++n) {
            const int pxl = (n << 4) + lo;
            const uint2 xv = *(const uint2*)&lds[4096 + swz(pxl, wb2)];
            const bool zero = row255 || (halfblk && pxl == 127);
            float xg0 = zero ? 0.f : bf2f(xv.x & 0xffffu) * sigm(acc[n][0]);
            float xg1 = zero ? 0.f : bf2f(xv.x >> 16)     * sigm(acc[n][1]);
            float xg2 = zero ? 0.f : bf2f(xv.y & 0xffffu) * sigm(acc[n][2]);
            float xg3 = zero ? 0.f : bf2f(xv.y >> 16)     * sigm(acc[n][3]);
            uint2 o;
            o.x = f2bf(xg0) | (f2bf(xg1) << 16);
            o.y = f2bf(xg2) | (f2bf(xg3) << 16);
            *(uint2*)&lds[swz(pxl, wb2)] = o;
        }
    }
    __syncthreads();

    // ---- GEMM2: d = dsc_w @ xg ----
    f32x4 acc2[8];
    #pragma unroll
    for (int n = 0; n < 8; ++n) acc2[n] = (f32x4){0.f, 0.f, 0.f, 0.f};
    #pragma unroll
    for (int n = 0; n < 8; ++n) {
        const int brow = (n << 4) + lo;
        const s16x8 b0 = __builtin_bit_cast(s16x8, *(const uint4*)&lds[swz(brow, hi << 2)]);
        const s16x8 b1 = __builtin_bit_cast(s16x8, *(const uint4*)&lds[swz(brow, (hi << 2) + 16)]);
        acc2[n] = __builtin_amdgcn_mfma_f32_16x16x32_bf16(ad0, b0, acc2[n], 0, 0, 0);
        acc2[n] = __builtin_amdgcn_mfma_f32_16x16x32_bf16(ad1, b1, acc2[n], 0, 0, 0);
    }

    // ---- epilogue: bias + GN partials + direct channel-last d stores ----
    float gs = 0.f, gq = 0.f;
    {
        const float4 bv = *(const float4*)(db + (wv << 4) + (hi << 2));
        unsigned short* dp = dbuf + (((size_t)b * HW + pbase) << 6) + (wv << 4) + (hi << 2);
        #pragma unroll
        for (int n = 0; n < 8; ++n) {
            const int pxl = (n << 4) + lo;
            const float d0 = acc2[n][0] + bv.x, d1 = acc2[n][1] + bv.y;
            const float d2 = acc2[n][2] + bv.z, d3 = acc2[n][3] + bv.w;
            gs += d0 + d1 + d2 + d3;
            gq += d0 * d0 + d1 * d1 + d2 * d2 + d3 * d3;
            uint2 o;
            o.x = f2bf(d0) | (f2bf(d1) << 16);
            o.y = f2bf(d2) | (f2bf(d3) << 16);
            *(uint2*)(dp + ((size_t)pxl << 6)) = o;
        }
    }
    #pragma unroll
    for (int o = 1; o < 16; o <<= 1) { gs += __shfl_xor(gs, o); gq += __shfl_xor(gq, o); }
    float* smf = (float*)&lds[8192];
    if (lo == 0) { smf[(((wv << 2) + hi) << 1)] = gs; smf[(((wv << 2) + hi) << 1) + 1] = gq; }
    __syncthreads();
    if (t < 16) {
        atomicAdd(&gn_sum[(b << 4) + t], smf[2 * t]);
        atomicAdd(&gn_sq[(b << 4) + t],  smf[2 * t + 1]);
    }
}

// ---------------------------------------------------------------------------
// P4 (k_bnstats): READ-ONLY pass: y = relu(GN(d)) + x computed in registers,
// BN stats accumulated into 8-way-spread scratch. No stores of y.
// grid = 2048 (256 px/block).
__global__ __launch_bounds__(256) void k_bnstats(
    const unsigned short* __restrict__ xpc, const unsigned short* __restrict__ dd,
    const float* __restrict__ gn_sum, const float* __restrict__ gn_sq,
    const float* __restrict__ gamma, const float* __restrict__ beta,
    float* __restrict__ bn_scr)
{
    const int t = threadIdx.x;
    const size_t P0 = (size_t)blockIdx.x << 8;
    const int b = (int)(P0 >> 16);
    __shared__ float ga[CB], gb[CB];
    __shared__ float red[4][128];
    if (t < CB) {
        const int g = t >> 2;
        const float n4 = 4.f * (float)HW;
        const float mu = gn_sum[b * 16 + g] / n4;
        const float var = gn_sq[b * 16 + g] / n4 - mu * mu;
        const float a = rsqrtf(var + 1e-5f) * gamma[t];
        ga[t] = a; gb[t] = beta[t] - mu * a;
    }
    __syncthreads();
    const int o8 = (t & 7) << 3;
    float ar[8], br[8];
    #pragma unroll
    for (int k = 0; k < 8; ++k) { ar[k] = ga[o8 + k]; br[k] = gb[o8 + k]; }
    float as[8], aq[8];
    #pragma unroll
    for (int k = 0; k < 8; ++k) { as[k] = 0.f; aq[k] = 0.f; }
    for (int i = 0; i < 8; ++i) {
        const size_t P = P0 + (i << 5) + (t >> 3);
        const size_t idx = (P << 6) + o8;
        const uint4 dv = *(const uint4*)(dd + idx);
        const uint4 xv = *(const uint4*)(xpc + idx);
        const unsigned dw_[4] = {dv.x, dv.y, dv.z, dv.w};
        const unsigned xw_[4] = {xv.x, xv.y, xv.z, xv.w};
        #pragma unroll
        for (int p = 0; p < 4; ++p) {
            const int k0 = 2 * p;
            const float y0 = fmaxf(bf2f(dw_[p] & 0xffffu) * ar[k0] + br[k0], 0.f) + bf2f(xw_[p] & 0xffffu);
            const float y1 = fmaxf(bf2f(dw_[p] >> 16) * ar[k0 + 1] + br[k0 + 1], 0.f) + bf2f(xw_[p] >> 16);
            as[k0] += y0; aq[k0] += y0 * y0;
            as[k0 + 1] += y1; aq[k0 + 1] += y1 * y1;
        }
    }
    #pragma unroll
    for (int k = 0; k < 8; ++k) {
        #pragma unroll
        for (int m = 8; m < 64; m <<= 1) {
            as[k] += __shfl_xor(as[k], m);
            aq[k] += __shfl_xor(aq[k], m);
        }
    }
    if ((t & 63) < 8) {
        const int o = t & 7, wvv = t >> 6;
        #pragma unroll
        for (int k = 0; k < 8; ++k) {
            red[wvv][o * 16 + k] = as[k];
            red[wvv][o * 16 + 8 + k] = aq[k];
        }
    }
    __syncthreads();
    if (t < 128) {
        const int o = t >> 4, st = (t >> 3) & 1, k = t & 7;
        const float v = red[0][t] + red[1][t] + red[2][t] + red[3][t];
        atomicAdd(&bn_scr[(blockIdx.x & 7) * 128 + st * 64 + o * 8 + k], v);
    }
}

// ---------------------------------------------------------------------------
// P5 (k_out): recompute y from d+xpc (L3-warm), BN finalize inlined,
// out = ob + sum_c ow[c]*prelu(BN(y)). grid = 2048.
__global__ __launch_bounds__(256) void k_out(
    const unsigned short* __restrict__ dd, const unsigned short* __restrict__ xpc,
    const float* __restrict__ gn_sum, const float* __restrict__ gn_sq,
    const float* __restrict__ gn_g, const float* __restrict__ gn_b,
    const float* __restrict__ bn_scr,
    const float* __restrict__ gamma, const float* __restrict__ beta,
    const float* __restrict__ pa, const float* __restrict__ ow,
    const float* __restrict__ ob, float* __restrict__ out)
{
    const int t = threadIdx.x;
    const size_t P0 = (size_t)blockIdx.x << 8;
    const int b = (int)(P0 >> 16);
    __shared__ float GA[CB], GB[CB], A[CB], Bs[CB], W[CB];
    if (t < CB) {
        // GN affine (same math as k_bnstats)
        const int g = t >> 2;
        const float n4 = 4.f * (float)HW;
        const float gmu = gn_sum[b * 16 + g] / n4;
        const float gvar = gn_sq[b * 16 + g] / n4 - gmu * gmu;
        const float a_ = rsqrtf(gvar + 1e-5f) * gn_g[t];
        GA[t] = a_; GB[t] = gn_b[t] - gmu * a_;
        // BN affine
        float s = 0.f, q = 0.f;
        #pragma unroll
        for (int r = 0; r < 8; ++r) { s += bn_scr[r * 128 + t]; q += bn_scr[r * 128 + 64 + t]; }
        const float n = (float)NB * (float)HW;
        const float mu = s / n;
        const float var = q / n - mu * mu;
        const float a2 = rsqrtf(var + 1e-5f) * gamma[t];
        A[t] = a2; Bs[t] = beta[t] - mu * a2; W[t] = ow[t];
    }
    __syncthreads();
    const size_t P = P0 + t;
    const unsigned short* dp = dd + (P << 6);
    const unsigned short* xp = xpc + (P << 6);
    const float alpha = pa[0];
    float acc = ob[0];
    #pragma unroll
    for (int q = 0; q < 8; ++q) {   // 8 x uint4 = 64 bf16 channels per pixel
        const uint4 dv = *(const uint4*)(dp + (q << 3));
        const uint4 xv = *(const uint4*)(xp + (q << 3));
        const unsigned dw_[4] = {dv.x, dv.y, dv.z, dv.w};
        const unsigned xw_[4] = {xv.x, xv.y, xv.z, xv.w};
        #pragma unroll
        for (int p = 0; p < 4; ++p) {
            const int c = (q << 3) + 2 * p;
            const float y0 = fmaxf(bf2f(dw_[p] & 0xffffu) * GA[c] + GB[c], 0.f) + bf2f(xw_[p] & 0xffffu);
            const float y1 = fmaxf(bf2f(dw_[p] >> 16) * GA[c + 1] + GB[c + 1], 0.f) + bf2f(xw_[p] >> 16);
            const float yb0 = bf2f(f2bf(y0));   // match bf16 round-trip of the old y store
            const float yb1 = bf2f(f2bf(y1));
            float z0 = yb0 * A[c] + Bs[c];
            float z1 = yb1 * A[c + 1] + Bs[c + 1];
            z0 = z0 >= 0.f ? z0 : alpha * z0;
            z1 = z1 >= 0.f ? z1 : alpha * z1;
            acc += W[c] * z0 + W[c + 1] * z1;
        }
    }
    out[P] = acc;
}

// ---------------------------------------------------------------------------
extern "C" void kernel_launch(void* const* d_in, const int* in_sizes, int n_in,
                              void* d_out, int out_size, void* d_ws, size_t ws_size,
                              hipStream_t stream)
{
    const float* x        = (const float*)d_in[0];
    const float* ca_w1    = (const float*)d_in[1];
    const float* ca_w2    = (const float*)d_in[2];
    const float* sa_w     = (const float*)d_in[3];
    const float* gate_w   = (const float*)d_in[4];
    // d_in[5..8]: offset branch — dead in forward math, skipped
    const float* dsc_w    = (const float*)d_in[9];
    const float* dsc_b    = (const float*)d_in[10];
    const float* gn_gamma = (const float*)d_in[11];
    const float* gn_beta  = (const float*)d_in[12];
    const float* bn_gamma = (const float*)d_in[13];
    const float* bn_beta  = (const float*)d_in[14];
    const float* prelu_a  = (const float*)d_in[15];
    const float* out_w    = (const float*)d_in[16];
    const float* out_b    = (const float*)d_in[17];
    float* out = (float*)d_out;

    char* ws = (char*)d_ws;
    size_t off = 0;
    auto alloc = [&](size_t bytes) -> char* {
        char* p = ws + off;
        off = (off + bytes + 255) & ~(size_t)255;
        return p;
    };
    unsigned short* dbuf = (unsigned short*)alloc((size_t)NB * HW * CB * 2);  // d, [px][ch]
    unsigned short* xpc  = (unsigned short*)alloc((size_t)NB * HW * CB * 2);  // bf16 x, [px][ch]
    unsigned* smb        = (unsigned*)alloc((size_t)NB * HW * 4);             // packed bf16 {mean,max}
    unsigned short* sab  = (unsigned short*)alloc((size_t)NB * HW * 2);       // bf16 spatial attn
    unsigned* wbuf       = (unsigned*)alloc(4096 * 4);                        // pre-swizzled bf16 weights
    float* cav           = (float*)alloc(512 * 4);
    float* pool_scr      = (float*)alloc(2048 * 64 * 4);                      // per-block pool sums
    float* pmax_scr      = (float*)alloc(2048 * 64 * 4);                      // per-block pool maxes
    float* zstats        = (float*)alloc(1280 * 4);                           // zeroed by k_pre tail
    float* gn_sum = zstats;          // [NB][16]
    float* gn_sq  = zstats + 128;    // [NB][16]
    float* bn_scr = zstats + 256;    // [8][128]
    (void)in_sizes; (void)n_in; (void)out_size; (void)ws_size;

    k_pre    <<<NB * 256 + 3, 256, 0, stream>>>(x, xpc, pool_scr, pmax_scr, smb,
                                                gate_w, dsc_w, wbuf, zstats);
    k_sa_ca  <<<NB * 256,     256, 0, stream>>>(smb, sa_w, pool_scr, pmax_scr,
                                                ca_w1, ca_w2, sab, cav);
    k_main   <<<NB * 512,     256, 0, stream>>>(xpc, sab, cav, wbuf, dsc_b,
                                                dbuf, gn_sum, gn_sq);
    k_bnstats<<<2048,         256, 0, stream>>>(xpc, dbuf, gn_sum, gn_sq,
                                                gn_gamma, gn_beta, bn_scr);
    k_out    <<<2048,         256, 0, stream>>>(dbuf, xpc, gn_sum, gn_sq,
                                                gn_gamma, gn_beta, bn_scr,
                                                bn_gamma, bn_beta,
                                                prelu_a, out_w, out_b, out);
}

// Round 13
// 159.310 us; speedup vs baseline: 1.2129x; 1.2129x over previous
//
#include <hip/hip_runtime.h>

#define HW 65536
#define CB 64
#define NB 8

typedef __attribute__((ext_vector_type(4))) float f32x4;
typedef __attribute__((ext_vector_type(8))) short s16x8;

__device__ __forceinline__ float sigm(float v) { return 1.f / (1.f + __expf(-v)); }

__device__ __forceinline__ unsigned f2bf(float f) {  // RNE, low 16 bits
    unsigned u = __float_as_uint(f);
    u += 0x7fffu + ((u >> 16) & 1u);
    return u >> 16;
}
__device__ __forceinline__ float bf2f(unsigned h) {
    return __uint_as_float(h << 16);
}
// swizzled word index for [row][32-word] bf16 tiles (row stride 128B)
__device__ __forceinline__ int swz(int row, int w) { return (row << 5) + (w ^ ((row & 7) << 2)); }

// ---------------------------------------------------------------------------
// P1 (k_pre): one pass over fp32 x ->
//   sm (per-px packed bf16 {channel-mean, channel-max}),
//   xpc (bf16 [px][64ch] copy via swizzled LDS transpose, coalesced dump),
//   per-channel pool sum/max partials (per-block slots, NO atomics/zeroing).
// Tail blocks (>=2048): convert gate/dsc weights to swizzled bf16 wbuf and
// zero the 1280-float gn/bn stats scratch (absorbs the old k_init dispatch).
// grid = NB*256 + 3, block = 256 (thread == pixel on the main path).
__global__ __launch_bounds__(256) void k_pre(
    const float* __restrict__ x, unsigned short* __restrict__ xpc,
    float* __restrict__ pool_scr, float* __restrict__ pmax_scr,
    unsigned* __restrict__ sm,
    const float* __restrict__ gw, const float* __restrict__ dw,
    unsigned* __restrict__ wbuf, float* __restrict__ zstats)
{
    const int t = threadIdx.x;
    if (blockIdx.x >= NB * 256) {          // ---- tail: init work ----
        const int ex = blockIdx.x - NB * 256;
        if (ex < 2) {
            const float* src = (ex == 0) ? gw : dw;
            unsigned* dst = wbuf + (ex << 11);
            const int orow = t >> 2, cq = (t & 3) << 4;
            const float* s = src + (orow << 6) + cq;
            unsigned u[8];
            #pragma unroll
            for (int j = 0; j < 8; ++j)
                u[j] = f2bf(s[2 * j]) | (f2bf(s[2 * j + 1]) << 16);
            const int wbase = (t & 3) << 3;
            *(uint4*)&dst[swz(orow, wbase)]     = make_uint4(u[0], u[1], u[2], u[3]);
            *(uint4*)&dst[swz(orow, wbase + 4)] = make_uint4(u[4], u[5], u[6], u[7]);
        } else {
            #pragma unroll
            for (int k2 = 0; k2 < 5; ++k2) zstats[k2 * 256 + t] = 0.f;
        }
        return;
    }

    __shared__ unsigned tile[8192];   // [256px][32 words] bf16, swizzled
    __shared__ float scrS[8][64];
    __shared__ float scrM[8][64];
    const int b = blockIdx.x >> 8;
    const int pbase = (blockIdx.x & 255) << 8;
    const size_t xb = ((size_t)(b << 6)) * HW + pbase + t;
    const int s = (t & 7) << 2;       // swizzle term for this thread's row

    float psum = 0.f, pmax = -1e30f;
    #pragma unroll
    for (int cg = 0; cg < 4; ++cg) {  // 16 channels per batch, all loads independent
        float v[16];
        #pragma unroll
        for (int k = 0; k < 16; ++k)
            v[k] = x[xb + (size_t)((cg << 4) + k) * HW];
        #pragma unroll
        for (int k = 0; k < 16; ++k) { psum += v[k]; pmax = fmaxf(pmax, v[k]); }
        unsigned w[8];
        #pragma unroll
        for (int k = 0; k < 8; ++k) w[k] = f2bf(v[2 * k]) | (f2bf(v[2 * k + 1]) << 16);
        *(uint4*)&tile[(t << 5) + (((cg << 3)) ^ s)]     = make_uint4(w[0], w[1], w[2], w[3]);
        *(uint4*)&tile[(t << 5) + (((cg << 3) + 4) ^ s)] = make_uint4(w[4], w[5], w[6], w[7]);
    }
    sm[(size_t)b * HW + pbase + t] = f2bf(psum * (1.f / 64.f)) | (f2bf(pmax) << 16);
    __syncthreads();

    // transposed per-channel reduce: cp = word (2 channels), q = px octant
    {
        const int cp = t & 31, q = t >> 5;
        float s0 = 0.f, s1 = 0.f, m0 = -1e30f, m1 = -1e30f;
        #pragma unroll 8
        for (int i = 0; i < 32; ++i) {
            const int px = (q << 5) + i;
            const unsigned u = tile[(px << 5) + (cp ^ ((px & 7) << 2))];
            const float a0 = bf2f(u & 0xffffu), a1 = bf2f(u >> 16);
            s0 += a0; s1 += a1;
            m0 = fmaxf(m0, a0); m1 = fmaxf(m1, a1);
        }
        scrS[q][2 * cp] = s0; scrS[q][2 * cp + 1] = s1;
        scrM[q][2 * cp] = m0; scrM[q][2 * cp + 1] = m1;
    }
    // coalesced xpc dump: thread t writes 16B at flat offset k*4096 + t*16
    {
        unsigned short* xp = xpc + (((size_t)b * HW + pbase) << 6);
        #pragma unroll
        for (int k = 0; k < 8; ++k) {
            const int px = (k << 5) + (t >> 3);
            const int w = ((t & 7) << 2) ^ ((px & 7) << 2);
            const uint4 v = *(const uint4*)&tile[(px << 5) + w];
            *(uint4*)(xp + (k << 11) + (t << 3)) = v;
        }
    }
    __syncthreads();
    if (t < 64) {        // per-block pool slot (no atomics, no init needed)
        float ss = 0.f, mm = -1e30f;
        #pragma unroll
        for (int q = 0; q < 8; ++q) { ss += scrS[q][t]; mm = fmaxf(mm, scrM[q][t]); }
        pool_scr[((size_t)blockIdx.x << 6) + t] = ss;
        pmax_scr[((size_t)blockIdx.x << 6) + t] = mm;
    }
}

// ---------------------------------------------------------------------------
// P2: 7x7 spatial-attention conv over packed bf16 {mean,max} maps (one uint
// load decodes both taps) + (row-0 blocks) channel-attention MLP. sa -> bf16.
__global__ __launch_bounds__(256) void k_sa_ca(
    const unsigned* __restrict__ sm, const float* __restrict__ w,
    const float* __restrict__ pool_scr, const float* __restrict__ pmax_scr,
    const float* __restrict__ w1, const float* __restrict__ w2,
    unsigned short* __restrict__ sa, float* __restrict__ ca)
{
    const int t = threadIdx.x;
    const int b = blockIdx.x >> 8;
    const int pix = ((blockIdx.x & 255) << 8) | t;
    const int i = pix >> 8, j = pix & 255;
    const unsigned* src = sm + (size_t)b * HW;
    float acc = 0.f;
    #pragma unroll
    for (int ki = 0; ki < 7; ++ki) {
        const int y = i + ki - 3;
        if ((unsigned)y < 256u) {
            #pragma unroll
            for (int kj = 0; kj < 7; ++kj) {
                const int xx = j + kj - 3;
                if ((unsigned)xx < 256u) {
                    const unsigned u = src[(y << 8) | xx];
                    acc += bf2f(u & 0xffffu) * w[ki * 7 + kj] +
                           bf2f(u >> 16)     * w[49 + ki * 7 + kj];
                }
            }
        }
    }
    sa[(size_t)b * HW + pix] = (unsigned short)f2bf(sigm(acc));

    if ((blockIdx.x & 255) == 0) {   // block-uniform branch: also compute ca[b]
        __shared__ float av[CB], mv[CB], hh[8];
        if (t < CB) {
            float ss = 0.f, mm = -1e30f;
            for (int r = 0; r < 256; ++r) {
                ss += pool_scr[(((size_t)(b << 8) + r) << 6) + t];
                mm = fmaxf(mm, pmax_scr[(((size_t)(b << 8) + r) << 6) + t]);
            }
            av[t] = ss * (1.f / (float)HW);
            mv[t] = mm;
        }
        __syncthreads();
        if (t < 8) {
            const int h = t & 3;
            const float* v = (t < 4) ? av : mv;
            float ssum = 0;
            for (int c = 0; c < CB; ++c) ssum += w1[h * CB + c] * v[c];
            hh[t] = fmaxf(ssum, 0.f);
        }
        __syncthreads();
        if (t < CB) {
            float ssum = 0;
            #pragma unroll
            for (int h = 0; h < 4; ++h) ssum += w2[t * 4 + h] * (hh[h] + hh[4 + h]);
            ca[b * CB + t] = sigm(ssum);
        }
    }
}

// ---------------------------------------------------------------------------
// P3 (k_main): MFMA main. 128-px tile/block, 4 waves, 4 blocks/CU (33KB LDS).
// A-fragments direct from pre-swizzled wbuf (L2). XT staging fused with FT
// compute (sa/ca direct from global). Two MFMA GEMMs; d + GN partials out.
// LDS: FT @0 (4096 words), XT @4096 (4096 words), smf @8192.
__global__ __launch_bounds__(256, 4) void k_main(
    const unsigned short* __restrict__ xpc, const unsigned short* __restrict__ sa,
    const float* __restrict__ ca, const unsigned* __restrict__ wbuf,
    const float* __restrict__ db,
    unsigned short* __restrict__ dbuf, float* __restrict__ gn_sum,
    float* __restrict__ gn_sq)
{
    __shared__ unsigned lds[8224];
    const int t = threadIdx.x;
    const int wv = t >> 6, l = t & 63, hi = l >> 4, lo = l & 15;
    const int b = blockIdx.x >> 9;
    const int pbase = (blockIdx.x & 511) << 7;

    // ---- A-fragments from pre-swizzled global wbuf (registers) ----
    const int arow = (wv << 4) + lo;
    const s16x8 ag0 = __builtin_bit_cast(s16x8, *(const uint4*)&wbuf[swz(arow, hi << 2)]);
    const s16x8 ag1 = __builtin_bit_cast(s16x8, *(const uint4*)&wbuf[swz(arow, (hi << 2) + 16)]);
    const s16x8 ad0 = __builtin_bit_cast(s16x8, *(const uint4*)&wbuf[2048 + swz(arow, hi << 2)]);
    const s16x8 ad1 = __builtin_bit_cast(s16x8, *(const uint4*)&wbuf[2048 + swz(arow, (hi << 2) + 16)]);

    // ---- stage XT (@4096) + FT (@0) fused: FT = x * (sa + ca) ----
    {
        const unsigned short* xp = xpc + (((size_t)b * HW + pbase) << 6);
        #pragma unroll
        for (int k = 0; k < 4; ++k) {
            const int idx = (k << 8) + t;      // 16B chunk id, flat
            const int px = idx >> 3;
            const int ch0 = (idx & 7) << 3;    // first channel of chunk
            const int wg = (idx & 7) << 2;     // logical word group
            const uint4 v = *(const uint4*)(xp + (idx << 3));
            const float sv = bf2f(sa[(size_t)b * HW + pbase + px]);
            const float4 cv0 = *(const float4*)(ca + (b << 6) + ch0);
            const float4 cv1 = *(const float4*)(ca + (b << 6) + ch0 + 4);
            uint4 fv;
            fv.x = f2bf(bf2f(v.x & 0xffffu) * (sv + cv0.x)) |
                   (f2bf(bf2f(v.x >> 16)    * (sv + cv0.y)) << 16);
            fv.y = f2bf(bf2f(v.y & 0xffffu) * (sv + cv0.z)) |
                   (f2bf(bf2f(v.y >> 16)    * (sv + cv0.w)) << 16);
            fv.z = f2bf(bf2f(v.z & 0xffffu) * (sv + cv1.x)) |
                   (f2bf(bf2f(v.z >> 16)    * (sv + cv1.y)) << 16);
            fv.w = f2bf(bf2f(v.w & 0xffffu) * (sv + cv1.z)) |
                   (f2bf(bf2f(v.w >> 16)    * (sv + cv1.w)) << 16);
            const int off = (px << 5) + (wg ^ ((px & 7) << 2));
            *(uint4*)&lds[4096 + off] = v;     // XT
            *(uint4*)&lds[off]        = fv;    // FT
        }
    }
    __syncthreads();

    // ---- GEMM1: guide logits = gate_w @ fuse ----
    f32x4 acc[8];
    #pragma unroll
    for (int n = 0; n < 8; ++n) acc[n] = (f32x4){0.f, 0.f, 0.f, 0.f};
    #pragma unroll
    for (int n = 0; n < 8; ++n) {
        const int brow = (n << 4) + lo;
        const s16x8 b0 = __builtin_bit_cast(s16x8, *(const uint4*)&lds[swz(brow, hi << 2)]);
        const s16x8 b1 = __builtin_bit_cast(s16x8, *(const uint4*)&lds[swz(brow, (hi << 2) + 16)]);
        acc[n] = __builtin_amdgcn_mfma_f32_16x16x32_bf16(ag0, b0, acc[n], 0, 0, 0);
        acc[n] = __builtin_amdgcn_mfma_f32_16x16x32_bf16(ag1, b1, acc[n], 0, 0, 0);
    }
    __syncthreads();

    // ---- xg = x * sigmoid(logit) * mask, XT(@4096) -> FT(@0) ----
    {
        const bool row255 = (pbase >> 8) == 255;
        const bool halfblk = (pbase & 128) != 0;
        const int wb2 = (wv << 3) + (hi << 1);
        #pragma unroll
        for (int n = 0; n < 8; ++n) {
            const int pxl = (n << 4) + lo;
            const uint2 xv = *(const uint2*)&lds[4096 + swz(pxl, wb2)];
            const bool zero = row255 || (halfblk && pxl == 127);
            float xg0 = zero ? 0.f : bf2f(xv.x & 0xffffu) * sigm(acc[n][0]);
            float xg1 = zero ? 0.f : bf2f(xv.x >> 16)     * sigm(acc[n][1]);
            float xg2 = zero ? 0.f : bf2f(xv.y & 0xffffu) * sigm(acc[n][2]);
            float xg3 = zero ? 0.f : bf2f(xv.y >> 16)     * sigm(acc[n][3]);
            uint2 o;
            o.x = f2bf(xg0) | (f2bf(xg1) << 16);
            o.y = f2bf(xg2) | (f2bf(xg3) << 16);
            *(uint2*)&lds[swz(pxl, wb2)] = o;
        }
    }
    __syncthreads();

    // ---- GEMM2: d = dsc_w @ xg ----
    f32x4 acc2[8];
    #pragma unroll
    for (int n = 0; n < 8; ++n) acc2[n] = (f32x4){0.f, 0.f, 0.f, 0.f};
    #pragma unroll
    for (int n = 0; n < 8; ++n) {
        const int brow = (n << 4) + lo;
        const s16x8 b0 = __builtin_bit_cast(s16x8, *(const uint4*)&lds[swz(brow, hi << 2)]);
        const s16x8 b1 = __builtin_bit_cast(s16x8, *(const uint4*)&lds[swz(brow, (hi << 2) + 16)]);
        acc2[n] = __builtin_amdgcn_mfma_f32_16x16x32_bf16(ad0, b0, acc2[n], 0, 0, 0);
        acc2[n] = __builtin_amdgcn_mfma_f32_16x16x32_bf16(ad1, b1, acc2[n], 0, 0, 0);
    }

    // ---- epilogue: bias + GN partials + direct channel-last d stores ----
    float gs = 0.f, gq = 0.f;
    {
        const float4 bv = *(const float4*)(db + (wv << 4) + (hi << 2));
        unsigned short* dp = dbuf + (((size_t)b * HW + pbase) << 6) + (wv << 4) + (hi << 2);
        #pragma unroll
        for (int n = 0; n < 8; ++n) {
            const int pxl = (n << 4) + lo;
            const float d0 = acc2[n][0] + bv.x, d1 = acc2[n][1] + bv.y;
            const float d2 = acc2[n][2] + bv.z, d3 = acc2[n][3] + bv.w;
            gs += d0 + d1 + d2 + d3;
            gq += d0 * d0 + d1 * d1 + d2 * d2 + d3 * d3;
            uint2 o;
            o.x = f2bf(d0) | (f2bf(d1) << 16);
            o.y = f2bf(d2) | (f2bf(d3) << 16);
            *(uint2*)(dp + ((size_t)pxl << 6)) = o;
        }
    }
    #pragma unroll
    for (int o = 1; o < 16; o <<= 1) { gs += __shfl_xor(gs, o); gq += __shfl_xor(gq, o); }
    float* smf = (float*)&lds[8192];
    if (lo == 0) { smf[(((wv << 2) + hi) << 1)] = gs; smf[(((wv << 2) + hi) << 1) + 1] = gq; }
    __syncthreads();
    if (t < 16) {
        atomicAdd(&gn_sum[(b << 4) + t], smf[2 * t]);
        atomicAdd(&gn_sq[(b << 4) + t],  smf[2 * t + 1]);
    }
}

// ---------------------------------------------------------------------------
// P4: y = relu(GN(d)) + x in-place on dbuf ([px][ch]); GN finalize inlined;
// BN stats into 8-way-spread scratch. grid = 2048 (256 px/block).
__global__ __launch_bounds__(256) void k_gnbn(
    const unsigned short* __restrict__ xpc, unsigned short* __restrict__ dy,
    const float* __restrict__ gn_sum, const float* __restrict__ gn_sq,
    const float* __restrict__ gamma, const float* __restrict__ beta,
    float* __restrict__ bn_scr)
{
    const int t = threadIdx.x;
    const size_t P0 = (size_t)blockIdx.x << 8;
    const int b = (int)(P0 >> 16);
    __shared__ float ga[CB], gb[CB];
    __shared__ float red[4][128];
    if (t < CB) {
        const int g = t >> 2;
        const float n4 = 4.f * (float)HW;
        const float mu = gn_sum[b * 16 + g] / n4;
        const float var = gn_sq[b * 16 + g] / n4 - mu * mu;
        const float a = rsqrtf(var + 1e-5f) * gamma[t];
        ga[t] = a; gb[t] = beta[t] - mu * a;
    }
    __syncthreads();
    const int o8 = (t & 7) << 3;
    float ar[8], br[8];
    #pragma unroll
    for (int k = 0; k < 8; ++k) { ar[k] = ga[o8 + k]; br[k] = gb[o8 + k]; }
    float as[8], aq[8];
    #pragma unroll
    for (int k = 0; k < 8; ++k) { as[k] = 0.f; aq[k] = 0.f; }
    for (int i = 0; i < 8; ++i) {
        const size_t P = P0 + (i << 5) + (t >> 3);
        const size_t idx = (P << 6) + o8;
        const uint4 dv = *(const uint4*)(dy + idx);
        const uint4 xv = *(const uint4*)(xpc + idx);
        const unsigned dw_[4] = {dv.x, dv.y, dv.z, dv.w};
        const unsigned xw_[4] = {xv.x, xv.y, xv.z, xv.w};
        uint4 o;
        unsigned ow_[4];
        #pragma unroll
        for (int p = 0; p < 4; ++p) {
            const int k0 = 2 * p;
            const float y0 = fmaxf(bf2f(dw_[p] & 0xffffu) * ar[k0] + br[k0], 0.f) + bf2f(xw_[p] & 0xffffu);
            const float y1 = fmaxf(bf2f(dw_[p] >> 16) * ar[k0 + 1] + br[k0 + 1], 0.f) + bf2f(xw_[p] >> 16);
            as[k0] += y0; aq[k0] += y0 * y0;
            as[k0 + 1] += y1; aq[k0 + 1] += y1 * y1;
            ow_[p] = f2bf(y0) | (f2bf(y1) << 16);
        }
        o.x = ow_[0]; o.y = ow_[1]; o.z = ow_[2]; o.w = ow_[3];
        *(uint4*)(dy + idx) = o;
    }
    #pragma unroll
    for (int k = 0; k < 8; ++k) {
        #pragma unroll
        for (int m = 8; m < 64; m <<= 1) {
            as[k] += __shfl_xor(as[k], m);
            aq[k] += __shfl_xor(aq[k], m);
        }
    }
    if ((t & 63) < 8) {
        const int o = t & 7, wvv = t >> 6;
        #pragma unroll
        for (int k = 0; k < 8; ++k) {
            red[wvv][o * 16 + k] = as[k];
            red[wvv][o * 16 + 8 + k] = aq[k];
        }
    }
    __syncthreads();
    if (t < 128) {
        const int o = t >> 4, st = (t >> 3) & 1, k = t & 7;
        const float v = red[0][t] + red[1][t] + red[2][t] + red[3][t];
        atomicAdd(&bn_scr[(blockIdx.x & 7) * 128 + st * 64 + o * 8 + k], v);
    }
}

// ---------------------------------------------------------------------------
// P5: out = ob + sum_c ow[c]*prelu(BN(y)); BN finalize inlined. grid = 2048.
__global__ __launch_bounds__(256) void k_out(
    const unsigned short* __restrict__ y, const float* __restrict__ bn_scr,
    const float* __restrict__ gamma, const float* __restrict__ beta,
    const float* __restrict__ pa, const float* __restrict__ ow,
    const float* __restrict__ ob, float* __restrict__ out)
{
    const int t = threadIdx.x;
    __shared__ float A[CB], Bs[CB], W[CB];
    if (t < CB) {
        float s = 0.f, q = 0.f;
        #pragma unroll
        for (int r = 0; r < 8; ++r) { s += bn_scr[r * 128 + t]; q += bn_scr[r * 128 + 64 + t]; }
        const float n = (float)NB * (float)HW;
        const float mu = s / n;
        const float var = q / n - mu * mu;
        const float a = rsqrtf(var + 1e-5f) * gamma[t];
        A[t] = a; Bs[t] = beta[t] - mu * a; W[t] = ow[t];
    }
    __syncthreads();
    const size_t P = ((size_t)blockIdx.x << 8) + t;
    const unsigned short* yp = y + (P << 6);
    const float alpha = pa[0];
    float acc = ob[0];
    #pragma unroll
    for (int q = 0; q < 8; ++q) {   // 8 x uint4 = 64 bf16 channels per pixel
        const uint4 v = *(const uint4*)(yp + (q << 3));
        const unsigned vw[4] = {v.x, v.y, v.z, v.w};
        #pragma unroll
        for (int p = 0; p < 4; ++p) {
            const int c = (q << 3) + 2 * p;
            float z0 = bf2f(vw[p] & 0xffffu) * A[c] + Bs[c];
            float z1 = bf2f(vw[p] >> 16) * A[c + 1] + Bs[c + 1];
            z0 = z0 >= 0.f ? z0 : alpha * z0;
            z1 = z1 >= 0.f ? z1 : alpha * z1;
            acc += W[c] * z0 + W[c + 1] * z1;
        }
    }
    out[P] = acc;
}

// ---------------------------------------------------------------------------
extern "C" void kernel_launch(void* const* d_in, const int* in_sizes, int n_in,
                              void* d_out, int out_size, void* d_ws, size_t ws_size,
                              hipStream_t stream)
{
    const float* x        = (const float*)d_in[0];
    const float* ca_w1    = (const float*)d_in[1];
    const float* ca_w2    = (const float*)d_in[2];
    const float* sa_w     = (const float*)d_in[3];
    const float* gate_w   = (const float*)d_in[4];
    // d_in[5..8]: offset branch — dead in forward math, skipped
    const float* dsc_w    = (const float*)d_in[9];
    const float* dsc_b    = (const float*)d_in[10];
    const float* gn_gamma = (const float*)d_in[11];
    const float* gn_beta  = (const float*)d_in[12];
    const float* bn_gamma = (const float*)d_in[13];
    const float* bn_beta  = (const float*)d_in[14];
    const float* prelu_a  = (const float*)d_in[15];
    const float* out_w    = (const float*)d_in[16];
    const float* out_b    = (const float*)d_in[17];
    float* out = (float*)d_out;

    char* ws = (char*)d_ws;
    size_t off = 0;
    auto alloc = [&](size_t bytes) -> char* {
        char* p = ws + off;
        off = (off + bytes + 255) & ~(size_t)255;
        return p;
    };
    unsigned short* dbuf = (unsigned short*)alloc((size_t)NB * HW * CB * 2);  // d -> y, [px][ch]
    unsigned short* xpc  = (unsigned short*)alloc((size_t)NB * HW * CB * 2);  // bf16 x, [px][ch]
    unsigned* smb        = (unsigned*)alloc((size_t)NB * HW * 4);             // packed bf16 {mean,max}
    unsigned short* sab  = (unsigned short*)alloc((size_t)NB * HW * 2);       // bf16 spatial attn
    unsigned* wbuf       = (unsigned*)alloc(4096 * 4);                        // pre-swizzled bf16 weights
    float* cav           = (float*)alloc(512 * 4);
    float* pool_scr      = (float*)alloc(2048 * 64 * 4);                      // per-block pool sums
    float* pmax_scr      = (float*)alloc(2048 * 64 * 4);                      // per-block pool maxes
    float* zstats        = (float*)alloc(1280 * 4);                           // zeroed by k_pre tail
    float* gn_sum = zstats;          // [NB][16]
    float* gn_sq  = zstats + 128;    // [NB][16]
    float* bn_scr = zstats + 256;    // [8][128]
    (void)in_sizes; (void)n_in; (void)out_size; (void)ws_size;

    k_pre  <<<NB * 256 + 3, 256, 0, stream>>>(x, xpc, pool_scr, pmax_scr, smb,
                                              gate_w, dsc_w, wbuf, zstats);
    k_sa_ca<<<NB * 256,     256, 0, stream>>>(smb, sa_w, pool_scr, pmax_scr,
                                              ca_w1, ca_w2, sab, cav);
    k_main <<<NB * 512,     256, 0, stream>>>(xpc, sab, cav, wbuf, dsc_b,
                                              dbuf, gn_sum, gn_sq);
    k_gnbn <<<2048,         256, 0, stream>>>(xpc, dbuf, gn_sum, gn_sq,
                                              gn_gamma, gn_beta, bn_scr);
    k_out  <<<2048,         256, 0, stream>>>(dbuf, bn_scr, bn_gamma, bn_beta,
                                              prelu_a, out_w, out_b, out);
}